// Round 10
// baseline (288.483 us; speedup 1.0000x reference)
//
#include <hip/hip_runtime.h>
#include <math.h>
#include <stdint.h>

#define TOKN 23040
#define BSZ 64
#define SEQ 360
#define DIM 256
#define NHD 8
#define HDD 32
#define MLPD 1024
#define NEGV -1e9f

typedef __attribute__((ext_vector_type(8))) short bf16x8;
typedef __attribute__((ext_vector_type(4))) float f32x4;

static __device__ __forceinline__ short f2bs(float f) {
  unsigned u = __builtin_bit_cast(unsigned, f);
  u += 0x7fffu + ((u >> 16) & 1u);
  return (short)(u >> 16);
}
static __device__ __forceinline__ float bf2f(short s) {
  unsigned u = ((unsigned)(unsigned short)s) << 16;
  return __builtin_bit_cast(float, u);
}
static __device__ __forceinline__ unsigned packbf(float a, float b) {
  return (unsigned)(unsigned short)f2bs(a) | ((unsigned)(unsigned short)f2bs(b) << 16);
}
// async global->LDS, 16B/lane; LDS dest = wave-uniform base + lane*16
static __device__ __forceinline__ void gl16(const short* g, short* l) {
  __builtin_amdgcn_global_load_lds(
      (const __attribute__((address_space(1))) unsigned int*)g,
      (__attribute__((address_space(3))) unsigned int*)l, 16, 0, 0);
}

// ================== mega front-end: MFMA router + convw + ln_router ==========
// Router: bf16 MFMA (64x128x256) + fp32 recheck of near-ties (threshold 0.004
// = 22 sigma of bf16 margin noise; flags ~6% = ~1400 tokens). Near-ties are
// APPENDED to a compact global list via atomicAdd (R9 post-mortem: strip-
// parallel recheck was latency-serial within blocks; parallelism must equal
// flagged-token count). List order nondeterminism is harmless: each token's
// recheck is independent and writes only sel[tok].
//   blocks [0,360)      : MFMA router (M=64 tokens/block)
//   blocks [360,1128)   : weight convert+transpose (32x32 LDS tiles)
//   blocks [1128,6888)  : LN1 + router weight-dot + passthrough, 4 tok/block
__global__ __launch_bounds__(256) void mega_k(
    const float* __restrict__ x, const float* __restrict__ g,
    const float* __restrict__ b, const float* __restrict__ wpw,
    const float* __restrict__ wpb, short* __restrict__ outn,
    float* __restrict__ wout, float* __restrict__ outx,
    const float* __restrict__ a1w, const float* __restrict__ a1b,
    const float* __restrict__ a2w, const float* __restrict__ a2b,
    int* __restrict__ sel, int* __restrict__ flagd,
    const float* __restrict__ wqkv, const float* __restrict__ wo,
    const float* __restrict__ w1, const float* __restrict__ w2,
    short* __restrict__ wqkvt, short* __restrict__ wot,
    short* __restrict__ w1t, short* __restrict__ w2t) {
  __shared__ __align__(16) unsigned char smem[13312];  // union across paths
  int bid = blockIdx.x;
  int t = threadIdx.x;

  if (bid < 360) {
    // ---- MFMA router: 64 tokens x 128 dims, K=256, bf16 in-kernel convert --
    short* As = (short*)smem;                 // 64x32 bf16 = 4096 B
    short* Ws = (short*)(smem + 4096);        // 128x32 bf16 = 8192 B
    float* r0s = (float*)(smem + 12288);      // [64][2] l0 partials
    float* r1s = (float*)(smem + 12800);      // [64][2] l1 partials
    int m0 = bid * 64;
    int wave = t >> 6, lane = t & 63;
    int l15 = lane & 15, quad = lane >> 4;
    int wr = (wave >> 1) * 32, wc = (wave & 1) * 64;
    int ar = t >> 2, akc = (t & 3) * 8;   // A staging: token row ar, k akc..+7
    int br = t >> 1, bkc = (t & 1) * 16;  // B staging: dim br, k bkc..+15
    const float* xp = x + (size_t)(m0 + ar) * 256 + akc;
    const float* wpA = a1w + (size_t)br * 256 + bkc;

    f32x4 acc[2][4];
#pragma unroll
    for (int i = 0; i < 2; i++)
#pragma unroll
      for (int j = 0; j < 4; j++)
#pragma unroll
        for (int r = 0; r < 4; r++) acc[i][j][r] = 0.f;

    for (int k0 = 0; k0 < 256; k0 += 32) {
      float4 xa = *(const float4*)(xp + k0);
      float4 xb = *(const float4*)(xp + k0 + 4);
      union { unsigned u[4]; int4 v; } px;
      px.u[0] = packbf(xa.x, xa.y); px.u[1] = packbf(xa.z, xa.w);
      px.u[2] = packbf(xb.x, xb.y); px.u[3] = packbf(xb.z, xb.w);
      *(int4*)&As[ar * 32 + akc] = px.v;
#pragma unroll
      for (int h2 = 0; h2 < 2; h2++) {
        float4 wa = *(const float4*)(wpA + k0 + h2 * 8);
        float4 wb = *(const float4*)(wpA + k0 + h2 * 8 + 4);
        union { unsigned u[4]; int4 v; } pw;
        pw.u[0] = packbf(wa.x, wa.y); pw.u[1] = packbf(wa.z, wa.w);
        pw.u[2] = packbf(wb.x, wb.y); pw.u[3] = packbf(wb.z, wb.w);
        *(int4*)&Ws[br * 32 + bkc + h2 * 8] = pw.v;
      }
      __syncthreads();
      bf16x8 af[2], bfr[4];
#pragma unroll
      for (int i = 0; i < 2; i++)
        af[i] = *(const bf16x8*)&As[(wr + i * 16 + l15) * 32 + quad * 8];
#pragma unroll
      for (int j = 0; j < 4; j++)
        bfr[j] = *(const bf16x8*)&Ws[(wc + j * 16 + l15) * 32 + quad * 8];
#pragma unroll
      for (int i = 0; i < 2; i++)
#pragma unroll
        for (int j = 0; j < 4; j++)
          acc[i][j] = __builtin_amdgcn_mfma_f32_16x16x32_bf16(af[i], bfr[j],
                                                              acc[i][j], 0, 0, 0);
      __syncthreads();
    }
    // epilogue: silu + a2 dot + per-row reduce (l15 shuffle, then wave-pair LDS)
    float bias0 = a2b[0], bias1 = a2b[1];
    float a1bc[4], a20c[4], a21c[4];
#pragma unroll
    for (int j = 0; j < 4; j++) {
      int col = wc + j * 16 + l15;
      a1bc[j] = a1b[col];
      a20c[j] = a2w[col];
      a21c[j] = a2w[128 + col];
    }
#pragma unroll
    for (int i = 0; i < 2; i++) {
#pragma unroll
      for (int r = 0; r < 4; r++) {
        float p0 = 0.f, p1 = 0.f;
#pragma unroll
        for (int j = 0; j < 4; j++) {
          float v = acc[i][j][r] + a1bc[j];
          float h = v / (1.f + expf(-v));
          p0 += h * a20c[j];
          p1 += h * a21c[j];
        }
#pragma unroll
        for (int o = 1; o < 16; o <<= 1) { p0 += __shfl_xor(p0, o); p1 += __shfl_xor(p1, o); }
        if (l15 == 0) {
          int lr = wr + i * 16 + quad * 4 + r;
          r0s[lr * 2 + (wave & 1)] = p0;
          r1s[lr * 2 + (wave & 1)] = p1;
        }
      }
    }
    __syncthreads();
    if ((wave & 1) == 0 && l15 == 0) {
#pragma unroll
      for (int i = 0; i < 2; i++)
#pragma unroll
        for (int r = 0; r < 4; r++) {
          int lr = wr + i * 16 + quad * 4 + r;
          float L0 = r0s[lr * 2] + r0s[lr * 2 + 1] + bias0;
          float L1 = r1s[lr * 2] + r1s[lr * 2 + 1] + bias1;
          sel[m0 + lr] = (L1 > L0) ? 1 : 0;
          if (fabsf(L1 - L0) < 0.004f) {
            int pos = atomicAdd(&flagd[0], 1);  // device-scope by default
            flagd[1 + pos] = m0 + lr;
          }
        }
    }
  } else if (bid < 1128) {
    // ---- convw: coalesced float4 reads, coalesced 8B bf16 writes ----
    float(*tile)[33] = (float(*)[33])smem;  // 4224 B
    int b2 = bid - 360;
    const float* src;
    short* dst;
    int K, N, kt, nt;
    if (b2 < 192) {
      src = wqkv; dst = wqkvt; K = 256; N = 768; kt = b2 / 24; nt = b2 % 24;
    } else if (b2 < 256) {
      int bb = b2 - 192; src = wo; dst = wot; K = 256; N = 256; kt = bb >> 3; nt = bb & 7;
    } else if (b2 < 512) {
      int bb = b2 - 256; src = w1; dst = w1t; K = 256; N = 1024; kt = bb >> 5; nt = bb & 31;
    } else {
      int bb = b2 - 512; src = w2; dst = w2t; K = 1024; N = 256; kt = bb >> 3; nt = bb & 7;
    }
    int r = t >> 3, c4 = (t & 7) * 4;
    const float4 v = *(const float4*)(src + (size_t)(kt * 32 + r) * N + nt * 32 + c4);
    tile[c4 + 0][r] = v.x;
    tile[c4 + 1][r] = v.y;
    tile[c4 + 2][r] = v.z;
    tile[c4 + 3][r] = v.w;
    __syncthreads();
    union { short s[4]; uint2 u; } o;
    o.s[0] = f2bs(tile[r][c4 + 0]);
    o.s[1] = f2bs(tile[r][c4 + 1]);
    o.s[2] = f2bs(tile[r][c4 + 2]);
    o.s[3] = f2bs(tile[r][c4 + 3]);
    *(uint2*)(dst + (size_t)(nt * 32 + r) * K + kt * 32 + c4) = o.u;
  } else {
    // ---- ln_router: LN1 + router weight dot + passthrough; 4 tokens/block ----
    int tok = (bid - 1128) * 4 + (t >> 6);
    int lane = t & 63;
    const float4 xv = *(const float4*)(x + (size_t)tok * DIM + lane * 4);
    *(float4*)(outx + (size_t)tok * DIM + lane * 4) = xv;
    float s = xv.x + xv.y + xv.z + xv.w;
    float s2 = xv.x * xv.x + xv.y * xv.y + xv.z * xv.z + xv.w * xv.w;
#pragma unroll
    for (int o = 1; o < 64; o <<= 1) { s += __shfl_xor(s, o); s2 += __shfl_xor(s2, o); }
    float m = s * (1.f / DIM);
    float var = fmaxf(s2 * (1.f / DIM) - m * m, 0.f);
    float rstd = rsqrtf(var + 1e-5f);
    float4 gv = *(const float4*)(g + lane * 4);
    float4 bv = *(const float4*)(b + lane * 4);
    uint2 pk;
    pk.x = packbf((xv.x - m) * rstd * gv.x + bv.x, (xv.y - m) * rstd * gv.y + bv.y);
    pk.y = packbf((xv.z - m) * rstd * gv.z + bv.z, (xv.w - m) * rstd * gv.w + bv.w);
    *(uint2*)(outn + (size_t)tok * DIM + lane * 4) = pk;
    float4 wv = *(const float4*)(wpw + lane * 4);
    float wd = xv.x * wv.x + xv.y * wv.y + xv.z * wv.z + xv.w * wv.w;
#pragma unroll
    for (int o = 1; o < 64; o <<= 1) wd += __shfl_xor(wd, o);
    if (lane == 0) wout[tok] = wd + wpb[0];
  }
}

// ================== fp32 recheck of near-tie router tokens (v4) =============
// R9 was still latency-serial (51.9us): strip-parallel blocks processed their
// flagged tokens sequentially (~5.6 blocks/CU, 2-4 serial ~2us chains each).
// v4: 1440 blocks grid-stride the COMPACT flag list (~1400 entries) -- one
// block per flagged token, all latency chains in parallel. The per-token
// 4-barrier fp32 pipeline (proven numerics) is byte-identical.
__global__ __launch_bounds__(256) void recheck_k(
    const float* __restrict__ x, const float* __restrict__ a1w,
    const float* __restrict__ a1b, const float* __restrict__ a2w,
    const float* __restrict__ a2b, const int* __restrict__ flagd,
    int* __restrict__ sel) {
  __shared__ __align__(16) float xs[256];
  __shared__ float ps[256];
  __shared__ float hs[128];
  int t = threadIdx.x;
  int n = flagd[0];
  const int* list = flagd + 1;
  for (int i = blockIdx.x; i < n; i += gridDim.x) {
    int tok = list[i];
    __syncthreads();  // guard xs/ps/hs reuse across list entries
    if (t < 64) *(float4*)&xs[t * 4] = *(const float4*)(x + (size_t)tok * 256 + t * 4);
    __syncthreads();
    int dim = t & 127, half = t >> 7;
    const float* wr = a1w + (size_t)dim * 256 + half * 128;
    const float* xr = &xs[half * 128];
    float p = 0.f;
#pragma unroll 8
    for (int k = 0; k < 128; k += 4) {
      float4 w4 = *(const float4*)(wr + k);
      p += xr[k] * w4.x + xr[k + 1] * w4.y + xr[k + 2] * w4.z + xr[k + 3] * w4.w;
    }
    ps[t] = p;
    __syncthreads();
    if (t < 128) {
      float v = ps[t] + ps[t + 128] + a1b[t];
      hs[t] = v / (1.f + expf(-v));
    }
    __syncthreads();
    if (t < 64) {
      float p0 = hs[t] * a2w[t] + hs[t + 64] * a2w[t + 64];
      float p1 = hs[t] * a2w[128 + t] + hs[t + 64] * a2w[128 + t + 64];
#pragma unroll
      for (int o = 1; o < 64; o <<= 1) { p0 += __shfl_xor(p0, o); p1 += __shfl_xor(p1, o); }
      if (t == 0) sel[tok] = (p1 + a2b[1] > p0 + a2b[0]) ? 1 : 0;
    }
  }
}

// ================== single-pass compaction ==================================
__global__ __launch_bounds__(512) void scan_k(
    const int* __restrict__ sel, int* __restrict__ g_idx,
    int* __restrict__ startp, int* __restrict__ cntp,
    int* __restrict__ mtotp, float* __restrict__ outavg) {
  __shared__ int sc[512];
  __shared__ int red[8];
  int b = blockIdx.x, t = threadIdx.x;
  int lane = t & 63, wave = t >> 6;
  int part = 0;
  for (int i = t; i < b * SEQ; i += 512) part += sel[i];
#pragma unroll
  for (int o = 1; o < 64; o <<= 1) part += __shfl_xor(part, o);
  if (lane == 0) red[wave] = part;
  __syncthreads();
  int start = 0;
#pragma unroll
  for (int w = 0; w < 8; w++) start += red[w];
  __syncthreads();
  int flag = (t < SEQ) ? sel[b * SEQ + t] : 0;
  sc[t] = flag;
  __syncthreads();
  int val = flag;
  for (int off = 1; off < 512; off <<= 1) {
    int add = (t >= off) ? sc[t - off] : 0;
    __syncthreads();
    val += add;
    sc[t] = val;
    __syncthreads();
  }
  if (flag) g_idx[start + val - 1] = b * SEQ + t;
  if (t == 511) { startp[b] = start; cntp[b] = val; }
  if (b == 63) {
    int mt = start + sc[511];
    if (t == 0) { *mtotp = mt; outavg[0] = (float)mt / 64.0f; }
    int e = mt + 256;
    if (e > TOKN) e = TOKN;
    for (int i = mt + t; i < e; i += 512) g_idx[i] = 0;  // pad rows -> token 0
  }
}

// ---------------- bf16 MFMA GEMM: 128xBN tile, double-buffered BK=32 stages.
// T3 2-phase (proven -10us in R4): STAGE(s+1) issued BEFORE compute of s;
// __syncthreads supplies the vmcnt(0)+barrier. K order = ascending 32-chunks.
template <int MODE, int BN>
__global__ __launch_bounds__(256) void gemm128_k(
    const short* __restrict__ A, const short* __restrict__ Bt,
    const float* __restrict__ bias, const float* __restrict__ resf,
    const short* __restrict__ resb, const float* __restrict__ wgt,
    const int* __restrict__ g_idx, const int* __restrict__ mtotp,
    short* __restrict__ outb, float* __restrict__ outf, int Ndim, int Kdim) {
  int Mt = *mtotp;
  int m0 = blockIdx.y * 128;
  if (m0 >= Mt) return;
  __shared__ __align__(16) short As[2][128 * 32];
  __shared__ __align__(16) short Bs[2][BN * 32];
  constexpr int NJ = BN / 32;
  int n0 = blockIdx.x * BN;
  int t = threadIdx.x;
  int wave = t >> 6, lane = t & 63;
  int l15 = lane & 15, quad = lane >> 4;
  int wr = (wave >> 1) * 64, wc = (wave & 1) * (BN / 2);
  int r0 = t >> 2, c0 = (t & 3) * 8;
  long arA = (MODE == 0) ? g_idx[m0 + r0] : (m0 + r0);
  long arB = (MODE == 0) ? g_idx[m0 + 64 + r0] : (m0 + 64 + r0);
  const short* gA0 = A + arA * Kdim + c0;
  const short* gA1 = A + arB * Kdim + c0;
  const short* gB0 = Bt + (size_t)(n0 + r0) * Kdim + c0;
  const short* gB1 = Bt + (size_t)(n0 + 64 + r0) * Kdim + c0;  // BN==128 only
  int wbase = wave * 512;  // wave-uniform LDS base; HW adds lane*16B

  f32x4 acc[4][NJ];
#pragma unroll
  for (int i = 0; i < 4; i++)
#pragma unroll
    for (int j = 0; j < NJ; j++)
#pragma unroll
      for (int r = 0; r < 4; r++) acc[i][j][r] = 0.f;

  int nst = Kdim >> 5;  // BK=32 stages
  gl16(gA0, As[0] + wbase);
  gl16(gA1, As[0] + 2048 + wbase);
  gl16(gB0, Bs[0] + wbase);
  if constexpr (BN == 128) gl16(gB1, Bs[0] + 2048 + wbase);
  __syncthreads();

  int buf = 0;
  for (int s = 0; s < nst; ++s) {
    if (s + 1 < nst) {
      int off = (s + 1) * 32;
      short* d = (buf ^ 1) ? &As[1][0] : &As[0][0];
      short* e = (buf ^ 1) ? &Bs[1][0] : &Bs[0][0];
      gl16(gA0 + off, d + wbase);
      gl16(gA1 + off, d + 2048 + wbase);
      gl16(gB0 + off, e + wbase);
      if constexpr (BN == 128) gl16(gB1 + off, e + 2048 + wbase);
    }
    const short* Ab = buf ? &As[1][0] : &As[0][0];
    const short* Bb = buf ? &Bs[1][0] : &Bs[0][0];
    bf16x8 af[4], bfr[NJ];
#pragma unroll
    for (int i = 0; i < 4; i++)
      af[i] = *(const bf16x8*)&Ab[(wr + i * 16 + l15) * 32 + quad * 8];
#pragma unroll
    for (int j = 0; j < NJ; j++)
      bfr[j] = *(const bf16x8*)&Bb[(wc + j * 16 + l15) * 32 + quad * 8];
#pragma unroll
    for (int i = 0; i < 4; i++)
#pragma unroll
      for (int j = 0; j < NJ; j++)
        acc[i][j] = __builtin_amdgcn_mfma_f32_16x16x32_bf16(af[i], bfr[j],
                                                            acc[i][j], 0, 0, 0);
    __syncthreads();
    buf ^= 1;
  }

#pragma unroll
  for (int i = 0; i < 4; i++) {
#pragma unroll
    for (int j = 0; j < NJ; j++) {
      int col = n0 + wc + j * 16 + l15;
      float bcol = bias[col];
#pragma unroll
      for (int r = 0; r < 4; r++) {
        int row = m0 + wr + i * 16 + quad * 4 + r;
        float v = acc[i][j][r] + bcol;
        size_t idx = (size_t)row * Ndim + col;
        if (MODE == 0) {
          outb[idx] = f2bs(v);
        } else if (MODE == 2) {
          float u = 0.7978845608028654f * (v + 0.044715f * v * v * v);
          float e = __expf(2.f * u);
          float th = 1.f - 2.f / (e + 1.f);
          outb[idx] = f2bs(0.5f * v * (1.f + th));
        } else {  // MODE 3: residual + weight scale, scatter to fp32 out
          if (row < Mt) {
            int orig = g_idx[row];
            float o = (v + bf2f(resb[idx])) * wgt[orig];
            outf[(size_t)orig * 256 + col] = o;
          }
        }
      }
    }
  }
}

// ================== fused wo-proj + residual + LN2 (R4 non-dbuf form) =======
__global__ __launch_bounds__(256) void wo_ln_k(
    const short* __restrict__ A, const short* __restrict__ Bt,
    const float* __restrict__ bias, const float* __restrict__ resf,
    const float* __restrict__ g2, const float* __restrict__ b2,
    const int* __restrict__ g_idx, const int* __restrict__ mtotp,
    short* __restrict__ h1b, short* __restrict__ h2n) {
  int Mt = *mtotp;
  int m0 = blockIdx.x * 128;
  if (m0 >= Mt) return;
  __shared__ __align__(16) short As0[128 * 32];
  __shared__ __align__(16) short As1[128 * 32];
  __shared__ __align__(16) short Bs0[256 * 32];
  __shared__ __align__(16) short Bs1[256 * 32];
  __shared__ float ps[128][2], ps2[128][2];
  int t = threadIdx.x;
  int wave = t >> 6, lane = t & 63;
  int l15 = lane & 15, quad = lane >> 4;
  int wr = (wave >> 1) * 64, wc = (wave & 1) * 128;
  int r0 = t >> 2, c0 = (t & 3) * 8;
  const short* gA0 = A + (size_t)(m0 + r0) * 256 + c0;
  const short* gA1 = A + (size_t)(m0 + 64 + r0) * 256 + c0;
  const short* gB0 = Bt + (size_t)r0 * 256 + c0;
  short* lA0 = As0 + wave * 512;
  short* lA1 = As1 + wave * 512;
  short* lB0 = Bs0 + wave * 512;
  short* lB1 = Bs1 + wave * 512;

  f32x4 acc[4][8];
#pragma unroll
  for (int i = 0; i < 4; i++)
#pragma unroll
    for (int j = 0; j < 8; j++)
#pragma unroll
      for (int r = 0; r < 4; r++) acc[i][j][r] = 0.f;

  for (int k0 = 0; k0 < 256; k0 += 64) {
    gl16(gA0 + k0, lA0);
    gl16(gA1 + k0, lA0 + 2048);
    gl16(gA0 + k0 + 32, lA1);
    gl16(gA1 + k0 + 32, lA1 + 2048);
#pragma unroll
    for (int q = 0; q < 4; q++) {
      gl16(gB0 + (size_t)q * 64 * 256 + k0, lB0 + q * 2048);
      gl16(gB0 + (size_t)q * 64 * 256 + k0 + 32, lB1 + q * 2048);
    }
    __syncthreads();
    bf16x8 af[4], bfr[8];
#pragma unroll
    for (int i = 0; i < 4; i++)
      af[i] = *(const bf16x8*)&As0[(wr + i * 16 + l15) * 32 + quad * 8];
#pragma unroll
    for (int j = 0; j < 8; j++)
      bfr[j] = *(const bf16x8*)&Bs0[(wc + j * 16 + l15) * 32 + quad * 8];
#pragma unroll
    for (int i = 0; i < 4; i++)
#pragma unroll
      for (int j = 0; j < 8; j++)
        acc[i][j] = __builtin_amdgcn_mfma_f32_16x16x32_bf16(af[i], bfr[j],
                                                            acc[i][j], 0, 0, 0);
#pragma unroll
    for (int i = 0; i < 4; i++)
      af[i] = *(const bf16x8*)&As1[(wr + i * 16 + l15) * 32 + quad * 8];
#pragma unroll
    for (int j = 0; j < 8; j++)
      bfr[j] = *(const bf16x8*)&Bs1[(wc + j * 16 + l15) * 32 + quad * 8];
#pragma unroll
    for (int i = 0; i < 4; i++)
#pragma unroll
      for (int j = 0; j < 8; j++)
        acc[i][j] = __builtin_amdgcn_mfma_f32_16x16x32_bf16(af[i], bfr[j],
                                                            acc[i][j], 0, 0, 0);
    __syncthreads();
  }

  float bcol[8], gcol[8], bbcol[8];
#pragma unroll
  for (int j = 0; j < 8; j++) {
    int col = wc + j * 16 + l15;
    bcol[j] = bias[col];
    gcol[j] = g2[col];
    bbcol[j] = b2[col];
  }
  float s1v[4][4], s2v[4][4];
#pragma unroll
  for (int i = 0; i < 4; i++) {
#pragma unroll
    for (int r = 0; r < 4; r++) {
      int row = m0 + wr + i * 16 + quad * 4 + r;
      int orig = g_idx[row];
      const float* xr = resf + (size_t)orig * 256;
      float ls_ = 0.f, ls2_ = 0.f;
#pragma unroll
      for (int j = 0; j < 8; j++) {
        int col = wc + j * 16 + l15;
        float h1 = acc[i][j][r] + bcol[j] + xr[col];
        acc[i][j][r] = h1;
        h1b[(size_t)row * 256 + col] = f2bs(h1);
        ls_ += h1;
        ls2_ += h1 * h1;
      }
      s1v[i][r] = ls_;
      s2v[i][r] = ls2_;
    }
  }
#pragma unroll
  for (int i = 0; i < 4; i++)
#pragma unroll
    for (int r = 0; r < 4; r++) {
#pragma unroll
      for (int o = 1; o < 16; o <<= 1) {
        s1v[i][r] += __shfl_xor(s1v[i][r], o);
        s2v[i][r] += __shfl_xor(s2v[i][r], o);
      }
    }
  if (l15 == 0) {
#pragma unroll
    for (int i = 0; i < 4; i++)
#pragma unroll
      for (int r = 0; r < 4; r++) {
        int lr = wr + i * 16 + quad * 4 + r;
        ps[lr][wave & 1] = s1v[i][r];
        ps2[lr][wave & 1] = s2v[i][r];
      }
  }
  __syncthreads();
#pragma unroll
  for (int i = 0; i < 4; i++) {
#pragma unroll
    for (int r = 0; r < 4; r++) {
      int lr = wr + i * 16 + quad * 4 + r;
      float S = ps[lr][0] + ps[lr][1];
      float S2 = ps2[lr][0] + ps2[lr][1];
      float m = S * (1.f / 256.f);
      float var = fmaxf(S2 * (1.f / 256.f) - m * m, 0.f);
      float rstd = rsqrtf(var + 1e-5f);
      int row = m0 + lr;
#pragma unroll
      for (int j = 0; j < 8; j++) {
        int col = wc + j * 16 + l15;
        float h2 = (acc[i][j][r] - m) * rstd * gcol[j] + bbcol[j];
        h2n[(size_t)row * 256 + col] = f2bs(h2);
      }
    }
  }
}

// ---------------- attention (compact, conflict-free V layout) ----------------
__global__ __launch_bounds__(256) void attn_k(
    const short* __restrict__ qkv, const float* __restrict__ amask,
    const int* __restrict__ g_idx, const int* __restrict__ startp,
    const int* __restrict__ cntp, short* __restrict__ ctx) {
  __shared__ __align__(16) short VF[2 * 12 * 64 * 8];
  __shared__ __align__(16) float ls[384];
  int bh = blockIdx.x >> 1, qhalf = blockIdx.x & 1;
  int bb = bh >> 3, h = bh & 7;
  int t = threadIdx.x;
  int start = startp[bb], cnt = cntp[bb];
  size_t base = (size_t)start * 768;
  for (int i = t; i < 1536; i += 256) {
    int k = i >> 2, cg = (i & 3) * 8;
    union { int4 v; short s[8]; } u;
    if (k < cnt) {
      u.v = *(const int4*)(qkv + base + (size_t)k * 768 + 512 + h * 32 + cg);
    } else {
      u.v = make_int4(0, 0, 0, 0);
    }
    int c = k >> 5, qd = (k >> 3) & 3, j = k & 7;
#pragma unroll
    for (int jj = 0; jj < 8; jj++) {
      int d = cg + jj;
      VF[((((d >> 4) * 12 + c) * 64) + qd * 16 + (d & 15)) * 8 + j] = u.s[jj];
    }
  }
  for (int i = t; i < 384; i += 256)
    ls[i] = (i < cnt) ? amask[g_idx[start + i]] : 0.f;
  __syncthreads();

  int wave = t >> 6, lane = t & 63;
  int ql = lane & 15, quad = lane >> 4;
  int addr0 = (((quad & 1) * 2) * 16 + ql) * 4;
  int addr1 = addr0 + 64;
  bool hiq = quad >= 2;
  int nt = (cnt + 15) >> 4;
  int nc = (cnt + 31) >> 5;

  for (int qt = qhalf + 2 * wave; qt < nt; qt += 8) {
    int q0 = qt * 16, qrow = q0 + ql;
    bf16x8 qf;
#pragma unroll
    for (int j = 0; j < 8; j++) qf[j] = 0;
    if (qrow < cnt)
      qf = *(const bf16x8*)(qkv + base + (size_t)qrow * 768 + h * 32 + quad * 8);

    f32x4 o0, o1;
#pragma unroll
    for (int r = 0; r < 4; r++) { o0[r] = 0.f; o1[r] = 0.f; }
    float lsum = 0.f;

    for (int c = 0; c < nc; c++) {
      int keyA = c * 32 + ql;
      int keyB = keyA + 16;
      bf16x8 kfA, kfB;
#pragma unroll
      for (int j = 0; j < 8; j++) { kfA[j] = 0; kfB[j] = 0; }
      if (keyA < cnt)
        kfA = *(const bf16x8*)(qkv + base + (size_t)keyA * 768 + 256 + h * 32 + quad * 8);
      if (keyB < cnt)
        kfB = *(const bf16x8*)(qkv + base + (size_t)keyB * 768 + 256 + h * 32 + quad * 8);
      f32x4 sa, sb;
#pragma unroll
      for (int r = 0; r < 4; r++) { sa[r] = 0.f; sb[r] = 0.f; }
      sa = __builtin_amdgcn_mfma_f32_16x16x32_bf16(kfA, qf, sa, 0, 0, 0);
      sb = __builtin_amdgcn_mfma_f32_16x16x32_bf16(kfB, qf, sb, 0, 0, 0);
      int kbase = c * 32 + quad * 4;
      float4 la = *(const float4*)&ls[kbase];
      float4 lb = *(const float4*)&ls[kbase + 16];
      float ea0 = (kbase + 0 < cnt) ? __expf(sa[0] * 0.17677669529663687f + la.x) : 0.f;
      float ea1 = (kbase + 1 < cnt) ? __expf(sa[1] * 0.17677669529663687f + la.y) : 0.f;
      float ea2 = (kbase + 2 < cnt) ? __expf(sa[2] * 0.17677669529663687f + la.z) : 0.f;
      float ea3 = (kbase + 3 < cnt) ? __expf(sa[3] * 0.17677669529663687f + la.w) : 0.f;
      float eb0 = (kbase + 16 < cnt) ? __expf(sb[0] * 0.17677669529663687f + lb.x) : 0.f;
      float eb1 = (kbase + 17 < cnt) ? __expf(sb[1] * 0.17677669529663687f + lb.y) : 0.f;
      float eb2 = (kbase + 18 < cnt) ? __expf(sb[2] * 0.17677669529663687f + lb.z) : 0.f;
      float eb3 = (kbase + 19 < cnt) ? __expf(sb[3] * 0.17677669529663687f + lb.w) : 0.f;
      lsum += (ea0 + ea1) + (ea2 + ea3) + (eb0 + eb1) + (eb2 + eb3);
      unsigned pA0 = packbf(ea0, ea1), pA1 = packbf(ea2, ea3);
      unsigned pB0 = packbf(eb0, eb1), pB1 = packbf(eb2, eb3);
      int s00 = __builtin_amdgcn_ds_bpermute(addr0, (int)pA0);
      int s10 = __builtin_amdgcn_ds_bpermute(addr0, (int)pB0);
      int s01 = __builtin_amdgcn_ds_bpermute(addr0, (int)pA1);
      int s11 = __builtin_amdgcn_ds_bpermute(addr0, (int)pB1);
      int s02 = __builtin_amdgcn_ds_bpermute(addr1, (int)pA0);
      int s12 = __builtin_amdgcn_ds_bpermute(addr1, (int)pB0);
      int s03 = __builtin_amdgcn_ds_bpermute(addr1, (int)pA1);
      int s13 = __builtin_amdgcn_ds_bpermute(addr1, (int)pB1);
      union { int i[4]; bf16x8 v; } pf;
      pf.i[0] = hiq ? s10 : s00;
      pf.i[1] = hiq ? s11 : s01;
      pf.i[2] = hiq ? s12 : s02;
      pf.i[3] = hiq ? s13 : s03;
      bf16x8 v0 = *(const bf16x8*)&VF[(c * 64 + lane) * 8];
      bf16x8 v1 = *(const bf16x8*)&VF[((12 + c) * 64 + lane) * 8];
      o0 = __builtin_amdgcn_mfma_f32_16x16x32_bf16(v0, pf.v, o0, 0, 0, 0);
      o1 = __builtin_amdgcn_mfma_f32_16x16x32_bf16(v1, pf.v, o1, 0, 0, 0);
    }
    lsum += __shfl_xor(lsum, 16);
    lsum += __shfl_xor(lsum, 32);
    float inv = 1.f / lsum;

    if (qrow < cnt) {
      size_t cb = ((size_t)(start + qrow)) * 256 + h * 32;
      uint2 w0, w1;
      w0.x = packbf(o0[0] * inv, o0[1] * inv);
      w0.y = packbf(o0[2] * inv, o0[3] * inv);
      w1.x = packbf(o1[0] * inv, o1[1] * inv);
      w1.y = packbf(o1[2] * inv, o1[3] * inv);
      *(uint2*)(ctx + cb + quad * 4) = w0;
      *(uint2*)(ctx + cb + 16 + quad * 4) = w1;
    }
  }
}

extern "C" void kernel_launch(void* const* d_in, const int* in_sizes, int n_in,
                              void* d_out, int out_size, void* d_ws,
                              size_t ws_size, hipStream_t stream) {
  const float* x = (const float*)d_in[0];
  const float* amask = (const float*)d_in[1];
  const float* wp_w = (const float*)d_in[2];
  const float* wp_b = (const float*)d_in[3];
  const float* a1_w = (const float*)d_in[4];
  const float* a1_b = (const float*)d_in[5];
  const float* a2_w = (const float*)d_in[6];
  const float* a2_b = (const float*)d_in[7];
  const float* ln1_g = (const float*)d_in[8];
  const float* ln1_b = (const float*)d_in[9];
  const float* wqkv = (const float*)d_in[10];
  const float* bqkv = (const float*)d_in[11];
  const float* wo = (const float*)d_in[12];
  const float* bo = (const float*)d_in[13];
  const float* ln2_g = (const float*)d_in[14];
  const float* ln2_b = (const float*)d_in[15];
  const float* w1 = (const float*)d_in[16];
  const float* b1 = (const float*)d_in[17];
  const float* w2 = (const float*)d_in[18];
  const float* b2 = (const float*)d_in[19];
  float* out = (float*)d_out;

  uint8_t* p = (uint8_t*)d_ws;
  float* weightsv = (float*)p; p += (size_t)TOKN * 4;
  int* selv = (int*)p;         p += (size_t)TOKN * 4;
  int* flagv = (int*)p;        p += (size_t)(TOKN + 64) * 4;  // [0]=count, [1..]=token list
  int* gidxv = (int*)p;        p += (size_t)TOKN * 4;
  int* cntv = (int*)p;         p += 64 * 4;
  int* startv = (int*)p;       p += 64 * 4;
  int* mtotv = (int*)p;        p += 64 * 4;
  short* wqkvt = (short*)p;    p += (size_t)768 * 256 * 2;
  short* wot = (short*)p;      p += (size_t)256 * 256 * 2;
  short* w1t = (short*)p;      p += (size_t)1024 * 256 * 2;
  short* w2t = (short*)p;      p += (size_t)256 * 1024 * 2;
  short* h1bv = (short*)p;     p += (size_t)TOKN * 256 * 2;
  short* h2nv = (short*)p;     p += (size_t)TOKN * 256 * 2;
  short* ctxv = (short*)p;     p += (size_t)TOKN * 256 * 2;
  uint8_t* R = p;
  short* xnv = (short*)R;
  short* qkvv = (short*)(R + (size_t)TOKN * 256 * 2);
  short* actv = (short*)R;

  // zero the flag-list counter (stream op; graph-capturable)
  hipMemsetAsync(flagv, 0, 4, stream);
  mega_k<<<dim3(6888), dim3(256), 0, stream>>>(
      x, ln1_g, ln1_b, wp_w, wp_b, xnv, weightsv, out,
      a1_w, a1_b, a2_w, a2_b, selv, flagv,
      wqkv, wo, w1, w2, wqkvt, wot, w1t, w2t);
  recheck_k<<<dim3(1440), dim3(256), 0, stream>>>(x, a1_w, a1_b, a2_w, a2_b,
                                                  flagv, selv);
  scan_k<<<dim3(64), dim3(512), 0, stream>>>(selv, gidxv, startv, cntv, mtotv,
                                             out + (size_t)TOKN * 256);
  gemm128_k<0, 128><<<dim3(6, 180), dim3(256), 0, stream>>>(
      xnv, wqkvt, bqkv, nullptr, nullptr, nullptr, gidxv, mtotv, qkvv, nullptr,
      768, 256);
  attn_k<<<dim3(1024), dim3(256), 0, stream>>>(qkvv, amask, gidxv, startv, cntv, ctxv);
  wo_ln_k<<<dim3(180), dim3(256), 0, stream>>>(ctxv, wot, bo, x, ln2_g, ln2_b,
                                               gidxv, mtotv, h1bv, h2nv);
  gemm128_k<2, 128><<<dim3(8, 180), dim3(256), 0, stream>>>(
      h2nv, w1t, b1, nullptr, nullptr, nullptr, gidxv, mtotv, actv, nullptr,
      1024, 256);
  gemm128_k<3, 64><<<dim3(4, 180), dim3(256), 0, stream>>>(
      actv, w2t, b2, nullptr, h1bv, weightsv, gidxv, mtotv, nullptr, out, 256, 1024);
}

// Round 11
// 243.282 us; speedup vs baseline: 1.1858x; 1.1858x over previous
//
#include <hip/hip_runtime.h>
#include <math.h>
#include <stdint.h>

#define TOKN 23040
#define BSZ 64
#define SEQ 360
#define DIM 256
#define NHD 8
#define HDD 32
#define MLPD 1024
#define NEGV -1e9f

typedef __attribute__((ext_vector_type(8))) short bf16x8;
typedef __attribute__((ext_vector_type(4))) float f32x4;

static __device__ __forceinline__ short f2bs(float f) {
  unsigned u = __builtin_bit_cast(unsigned, f);
  u += 0x7fffu + ((u >> 16) & 1u);
  return (short)(u >> 16);
}
static __device__ __forceinline__ float bf2f(short s) {
  unsigned u = ((unsigned)(unsigned short)s) << 16;
  return __builtin_bit_cast(float, u);
}
static __device__ __forceinline__ unsigned packbf(float a, float b) {
  return (unsigned)(unsigned short)f2bs(a) | ((unsigned)(unsigned short)f2bs(b) << 16);
}
// async global->LDS, 16B/lane; LDS dest = wave-uniform base + lane*16
static __device__ __forceinline__ void gl16(const short* g, short* l) {
  __builtin_amdgcn_global_load_lds(
      (const __attribute__((address_space(1))) unsigned int*)g,
      (__attribute__((address_space(3))) unsigned int*)l, 16, 0, 0);
}

// ================== mega front-end: router_gemm + convw + ln_router ==========
// R4-exact restore (best measured: 243.5us). The R7-R10 bf16-MFMA-router +
// recheck arc measured SLOWER (mega 52-58 vs <=42.6 here) and is abandoned.
//   blocks [0,720)      : router a1 GEMM (fp32) + silu + a2 + argmax -> sel
//   blocks [720,1488)   : weight convert+transpose (32x32 LDS tiles)
//   blocks [1488,7248)  : LN1 + router weight-dot + fp32 passthrough copy
__global__ __launch_bounds__(256) void mega_k(
    const float* __restrict__ x, const float* __restrict__ g,
    const float* __restrict__ b, const float* __restrict__ wpw,
    const float* __restrict__ wpb, short* __restrict__ outn,
    float* __restrict__ wout, float* __restrict__ outx,
    const float* __restrict__ a1w, const float* __restrict__ a1b,
    const float* __restrict__ a2w, const float* __restrict__ a2b,
    int* __restrict__ sel,
    const float* __restrict__ wqkv, const float* __restrict__ wo,
    const float* __restrict__ w1, const float* __restrict__ w2,
    short* __restrict__ wqkvt, short* __restrict__ wot,
    short* __restrict__ w1t, short* __restrict__ w2t) {
  __shared__ __align__(16) unsigned char smem[20992];  // union across paths
  int bid = blockIdx.x;
  int t = threadIdx.x;

  if (bid < 720) {
    // ---- router: M=32 tile. fp32 throughout (bf16 logits flip argmax). ----
    float(*XT)[36] = (float(*)[36])smem;            // 4608 B
    float(*WT)[128] = (float(*)[128])(smem + 4608); // 16384 B
    int m0 = bid * 32;
    int tx = t & 31, ty = t >> 5;
    float acc[4][4] = {};
    int r = t >> 3, c = (t & 7) * 4;
    int n2 = t >> 1, c2 = (t & 1) * 16;
    for (int k0 = 0; k0 < 256; k0 += 32) {
      float4 xa = *(const float4*)(x + (size_t)(m0 + r) * 256 + k0 + c);
      XT[c + 0][r] = xa.x; XT[c + 1][r] = xa.y; XT[c + 2][r] = xa.z; XT[c + 3][r] = xa.w;
#pragma unroll
      for (int j = 0; j < 4; j++) {
        float4 wv = *(const float4*)(a1w + (size_t)n2 * 256 + k0 + c2 + j * 4);
        WT[c2 + j * 4 + 0][n2] = wv.x;
        WT[c2 + j * 4 + 1][n2] = wv.y;
        WT[c2 + j * 4 + 2][n2] = wv.z;
        WT[c2 + j * 4 + 3][n2] = wv.w;
      }
      __syncthreads();
#pragma unroll 8
      for (int kk = 0; kk < 32; kk++) {
        float4 wv4 = *(const float4*)&WT[kk][tx * 4];
        float4 xv4 = *(const float4*)&XT[kk][ty * 4];
        float xr[4] = {xv4.x, xv4.y, xv4.z, xv4.w};
        float wr[4] = {wv4.x, wv4.y, wv4.z, wv4.w};
#pragma unroll
        for (int i = 0; i < 4; i++)
#pragma unroll
          for (int j = 0; j < 4; j++) acc[i][j] += xr[i] * wr[j];
      }
      __syncthreads();
    }
    float b1v[4], a20[4], a21[4];
#pragma unroll
    for (int j = 0; j < 4; j++) {
      int dim = tx * 4 + j;
      b1v[j] = a1b[dim];
      a20[j] = a2w[dim];
      a21[j] = a2w[128 + dim];
    }
    float bias0 = a2b[0], bias1 = a2b[1];
#pragma unroll
    for (int i = 0; i < 4; i++) {
      float l0 = 0.f, l1 = 0.f;
#pragma unroll
      for (int j = 0; j < 4; j++) {
        float v = acc[i][j] + b1v[j];
        float h = v / (1.f + expf(-v));
        l0 += h * a20[j];
        l1 += h * a21[j];
      }
#pragma unroll
      for (int o = 1; o < 32; o <<= 1) { l0 += __shfl_xor(l0, o); l1 += __shfl_xor(l1, o); }
      if (tx == 0) sel[m0 + ty * 4 + i] = (l1 + bias1 > l0 + bias0) ? 1 : 0;
    }
  } else if (bid < 1488) {
    // ---- convw: coalesced float4 reads, coalesced 8B bf16 writes ----
    float(*tile)[33] = (float(*)[33])smem;  // 4224 B
    int b2 = bid - 720;
    const float* src;
    short* dst;
    int K, N, kt, nt;
    if (b2 < 192) {
      src = wqkv; dst = wqkvt; K = 256; N = 768; kt = b2 / 24; nt = b2 % 24;
    } else if (b2 < 256) {
      int bb = b2 - 192; src = wo; dst = wot; K = 256; N = 256; kt = bb >> 3; nt = bb & 7;
    } else if (b2 < 512) {
      int bb = b2 - 256; src = w1; dst = w1t; K = 256; N = 1024; kt = bb >> 5; nt = bb & 31;
    } else {
      int bb = b2 - 512; src = w2; dst = w2t; K = 1024; N = 256; kt = bb >> 3; nt = bb & 7;
    }
    int r = t >> 3, c4 = (t & 7) * 4;
    const float4 v = *(const float4*)(src + (size_t)(kt * 32 + r) * N + nt * 32 + c4);
    tile[c4 + 0][r] = v.x;
    tile[c4 + 1][r] = v.y;
    tile[c4 + 2][r] = v.z;
    tile[c4 + 3][r] = v.w;
    __syncthreads();
    union { short s[4]; uint2 u; } o;
    o.s[0] = f2bs(tile[r][c4 + 0]);
    o.s[1] = f2bs(tile[r][c4 + 1]);
    o.s[2] = f2bs(tile[r][c4 + 2]);
    o.s[3] = f2bs(tile[r][c4 + 3]);
    *(uint2*)(dst + (size_t)(nt * 32 + r) * K + kt * 32 + c4) = o.u;
  } else {
    // ---- ln_router: LN1 + router weight dot + passthrough; 4 tokens/block ----
    int tok = (bid - 1488) * 4 + (t >> 6);
    int lane = t & 63;
    const float4 xv = *(const float4*)(x + (size_t)tok * DIM + lane * 4);
    *(float4*)(outx + (size_t)tok * DIM + lane * 4) = xv;
    float s = xv.x + xv.y + xv.z + xv.w;
    float s2 = xv.x * xv.x + xv.y * xv.y + xv.z * xv.z + xv.w * xv.w;
#pragma unroll
    for (int o = 1; o < 64; o <<= 1) { s += __shfl_xor(s, o); s2 += __shfl_xor(s2, o); }
    float m = s * (1.f / DIM);
    float var = fmaxf(s2 * (1.f / DIM) - m * m, 0.f);
    float rstd = rsqrtf(var + 1e-5f);
    float4 gv = *(const float4*)(g + lane * 4);
    float4 bv = *(const float4*)(b + lane * 4);
    uint2 pk;
    pk.x = packbf((xv.x - m) * rstd * gv.x + bv.x, (xv.y - m) * rstd * gv.y + bv.y);
    pk.y = packbf((xv.z - m) * rstd * gv.z + bv.z, (xv.w - m) * rstd * gv.w + bv.w);
    *(uint2*)(outn + (size_t)tok * DIM + lane * 4) = pk;
    float4 wv = *(const float4*)(wpw + lane * 4);
    float wd = xv.x * wv.x + xv.y * wv.y + xv.z * wv.z + xv.w * wv.w;
#pragma unroll
    for (int o = 1; o < 64; o <<= 1) wd += __shfl_xor(wd, o);
    if (lane == 0) wout[tok] = wd + wpb[0];
  }
}

// ================== single-pass compaction ==================================
__global__ __launch_bounds__(512) void scan_k(
    const int* __restrict__ sel, int* __restrict__ g_idx,
    int* __restrict__ startp, int* __restrict__ cntp,
    int* __restrict__ mtotp, float* __restrict__ outavg) {
  __shared__ int sc[512];
  __shared__ int red[8];
  int b = blockIdx.x, t = threadIdx.x;
  int lane = t & 63, wave = t >> 6;
  int part = 0;
  for (int i = t; i < b * SEQ; i += 512) part += sel[i];
#pragma unroll
  for (int o = 1; o < 64; o <<= 1) part += __shfl_xor(part, o);
  if (lane == 0) red[wave] = part;
  __syncthreads();
  int start = 0;
#pragma unroll
  for (int w = 0; w < 8; w++) start += red[w];
  __syncthreads();
  int flag = (t < SEQ) ? sel[b * SEQ + t] : 0;
  sc[t] = flag;
  __syncthreads();
  int val = flag;
  for (int off = 1; off < 512; off <<= 1) {
    int add = (t >= off) ? sc[t - off] : 0;
    __syncthreads();
    val += add;
    sc[t] = val;
    __syncthreads();
  }
  if (flag) g_idx[start + val - 1] = b * SEQ + t;
  if (t == 511) { startp[b] = start; cntp[b] = val; }
  if (b == 63) {
    int mt = start + sc[511];
    if (t == 0) { *mtotp = mt; outavg[0] = (float)mt / 64.0f; }
    int e = mt + 256;
    if (e > TOKN) e = TOKN;
    for (int i = mt + t; i < e; i += 512) g_idx[i] = 0;  // pad rows -> token 0
  }
}

// ---------------- bf16 MFMA GEMM: 128xBN tile, double-buffered BK=32 stages.
// T3 2-phase (proven -10us in R4): STAGE(s+1) issued BEFORE compute of s;
// __syncthreads supplies the vmcnt(0)+barrier. K order = ascending 32-chunks.
template <int MODE, int BN>
__global__ __launch_bounds__(256) void gemm128_k(
    const short* __restrict__ A, const short* __restrict__ Bt,
    const float* __restrict__ bias, const float* __restrict__ resf,
    const short* __restrict__ resb, const float* __restrict__ wgt,
    const int* __restrict__ g_idx, const int* __restrict__ mtotp,
    short* __restrict__ outb, float* __restrict__ outf, int Ndim, int Kdim) {
  int Mt = *mtotp;
  int m0 = blockIdx.y * 128;
  if (m0 >= Mt) return;
  __shared__ __align__(16) short As[2][128 * 32];
  __shared__ __align__(16) short Bs[2][BN * 32];
  constexpr int NJ = BN / 32;
  int n0 = blockIdx.x * BN;
  int t = threadIdx.x;
  int wave = t >> 6, lane = t & 63;
  int l15 = lane & 15, quad = lane >> 4;
  int wr = (wave >> 1) * 64, wc = (wave & 1) * (BN / 2);
  int r0 = t >> 2, c0 = (t & 3) * 8;
  long arA = (MODE == 0) ? g_idx[m0 + r0] : (m0 + r0);
  long arB = (MODE == 0) ? g_idx[m0 + 64 + r0] : (m0 + 64 + r0);
  const short* gA0 = A + arA * Kdim + c0;
  const short* gA1 = A + arB * Kdim + c0;
  const short* gB0 = Bt + (size_t)(n0 + r0) * Kdim + c0;
  const short* gB1 = Bt + (size_t)(n0 + 64 + r0) * Kdim + c0;  // BN==128 only
  int wbase = wave * 512;  // wave-uniform LDS base; HW adds lane*16B

  f32x4 acc[4][NJ];
#pragma unroll
  for (int i = 0; i < 4; i++)
#pragma unroll
    for (int j = 0; j < NJ; j++)
#pragma unroll
      for (int r = 0; r < 4; r++) acc[i][j][r] = 0.f;

  int nst = Kdim >> 5;  // BK=32 stages
  gl16(gA0, As[0] + wbase);
  gl16(gA1, As[0] + 2048 + wbase);
  gl16(gB0, Bs[0] + wbase);
  if constexpr (BN == 128) gl16(gB1, Bs[0] + 2048 + wbase);
  __syncthreads();

  int buf = 0;
  for (int s = 0; s < nst; ++s) {
    if (s + 1 < nst) {
      int off = (s + 1) * 32;
      short* d = (buf ^ 1) ? &As[1][0] : &As[0][0];
      short* e = (buf ^ 1) ? &Bs[1][0] : &Bs[0][0];
      gl16(gA0 + off, d + wbase);
      gl16(gA1 + off, d + 2048 + wbase);
      gl16(gB0 + off, e + wbase);
      if constexpr (BN == 128) gl16(gB1 + off, e + 2048 + wbase);
    }
    const short* Ab = buf ? &As[1][0] : &As[0][0];
    const short* Bb = buf ? &Bs[1][0] : &Bs[0][0];
    bf16x8 af[4], bfr[NJ];
#pragma unroll
    for (int i = 0; i < 4; i++)
      af[i] = *(const bf16x8*)&Ab[(wr + i * 16 + l15) * 32 + quad * 8];
#pragma unroll
    for (int j = 0; j < NJ; j++)
      bfr[j] = *(const bf16x8*)&Bb[(wc + j * 16 + l15) * 32 + quad * 8];
#pragma unroll
    for (int i = 0; i < 4; i++)
#pragma unroll
      for (int j = 0; j < NJ; j++)
        acc[i][j] = __builtin_amdgcn_mfma_f32_16x16x32_bf16(af[i], bfr[j],
                                                            acc[i][j], 0, 0, 0);
    __syncthreads();
    buf ^= 1;
  }

#pragma unroll
  for (int i = 0; i < 4; i++) {
#pragma unroll
    for (int j = 0; j < NJ; j++) {
      int col = n0 + wc + j * 16 + l15;
      float bcol = bias[col];
#pragma unroll
      for (int r = 0; r < 4; r++) {
        int row = m0 + wr + i * 16 + quad * 4 + r;
        float v = acc[i][j][r] + bcol;
        size_t idx = (size_t)row * Ndim + col;
        if (MODE == 0) {
          outb[idx] = f2bs(v);
        } else if (MODE == 2) {
          float u = 0.7978845608028654f * (v + 0.044715f * v * v * v);
          float e = __expf(2.f * u);
          float th = 1.f - 2.f / (e + 1.f);
          outb[idx] = f2bs(0.5f * v * (1.f + th));
        } else {  // MODE 3: residual + weight scale, scatter to fp32 out
          if (row < Mt) {
            int orig = g_idx[row];
            float o = (v + bf2f(resb[idx])) * wgt[orig];
            outf[(size_t)orig * 256 + col] = o;
          }
        }
      }
    }
  }
}

// ================== fused wo-proj + residual + LN2 (64-row tiles) ===========
// R10 profile: the 128-row version ran at 52-54us with 3% occupancy -- only
// ~90 ACTIVE blocks (Mt/128) = 0.35/CU, pure latency exposure. 64-row tiles
// double active blocks to ~180 (0.7/CU) and cut LDS 51->41KB. Per-row math,
// K-order (ascending 64-chunks, As0 then As1) and the LN reduction structure
// (l15 shuffle + wave-pair LDS combine) are bit-identical to the 128-row
// form -- only the row extent per block changes.
__global__ __launch_bounds__(256) void wo_ln_k(
    const short* __restrict__ A, const short* __restrict__ Bt,
    const float* __restrict__ bias, const float* __restrict__ resf,
    const float* __restrict__ g2, const float* __restrict__ b2,
    const int* __restrict__ g_idx, const int* __restrict__ mtotp,
    short* __restrict__ h1b, short* __restrict__ h2n) {
  int Mt = *mtotp;
  int m0 = blockIdx.x * 64;
  if (m0 >= Mt) return;
  __shared__ __align__(16) short As0[64 * 32];
  __shared__ __align__(16) short As1[64 * 32];
  __shared__ __align__(16) short Bs0[256 * 32];
  __shared__ __align__(16) short Bs1[256 * 32];
  __shared__ float ps[64][2], ps2[64][2];
  int t = threadIdx.x;
  int wave = t >> 6, lane = t & 63;
  int l15 = lane & 15, quad = lane >> 4;
  int wr = (wave >> 1) * 32, wc = (wave & 1) * 128;
  int r0 = t >> 2, c0 = (t & 3) * 8;
  const short* gA0 = A + (size_t)(m0 + r0) * 256 + c0;
  const short* gB0 = Bt + (size_t)r0 * 256 + c0;
  short* lA0 = As0 + wave * 512;  // wave-uniform base; HW adds lane*16B
  short* lA1 = As1 + wave * 512;
  short* lB0 = Bs0 + wave * 512;
  short* lB1 = Bs1 + wave * 512;

  f32x4 acc[2][8];
#pragma unroll
  for (int i = 0; i < 2; i++)
#pragma unroll
    for (int j = 0; j < 8; j++)
#pragma unroll
      for (int r = 0; r < 4; r++) acc[i][j][r] = 0.f;

  for (int k0 = 0; k0 < 256; k0 += 64) {
    gl16(gA0 + k0, lA0);
    gl16(gA0 + k0 + 32, lA1);
#pragma unroll
    for (int q = 0; q < 4; q++) {
      gl16(gB0 + (size_t)q * 64 * 256 + k0, lB0 + q * 2048);
      gl16(gB0 + (size_t)q * 64 * 256 + k0 + 32, lB1 + q * 2048);
    }
    __syncthreads();
    bf16x8 af[2], bfr[8];
#pragma unroll
    for (int i = 0; i < 2; i++)
      af[i] = *(const bf16x8*)&As0[(wr + i * 16 + l15) * 32 + quad * 8];
#pragma unroll
    for (int j = 0; j < 8; j++)
      bfr[j] = *(const bf16x8*)&Bs0[(wc + j * 16 + l15) * 32 + quad * 8];
#pragma unroll
    for (int i = 0; i < 2; i++)
#pragma unroll
      for (int j = 0; j < 8; j++)
        acc[i][j] = __builtin_amdgcn_mfma_f32_16x16x32_bf16(af[i], bfr[j],
                                                            acc[i][j], 0, 0, 0);
#pragma unroll
    for (int i = 0; i < 2; i++)
      af[i] = *(const bf16x8*)&As1[(wr + i * 16 + l15) * 32 + quad * 8];
#pragma unroll
    for (int j = 0; j < 8; j++)
      bfr[j] = *(const bf16x8*)&Bs1[(wc + j * 16 + l15) * 32 + quad * 8];
#pragma unroll
    for (int i = 0; i < 2; i++)
#pragma unroll
      for (int j = 0; j < 8; j++)
        acc[i][j] = __builtin_amdgcn_mfma_f32_16x16x32_bf16(af[i], bfr[j],
                                                            acc[i][j], 0, 0, 0);
    __syncthreads();
  }

  float bcol[8], gcol[8], bbcol[8];
#pragma unroll
  for (int j = 0; j < 8; j++) {
    int col = wc + j * 16 + l15;
    bcol[j] = bias[col];
    gcol[j] = g2[col];
    bbcol[j] = b2[col];
  }
  float s1v[2][4], s2v[2][4];
#pragma unroll
  for (int i = 0; i < 2; i++) {
#pragma unroll
    for (int r = 0; r < 4; r++) {
      int row = m0 + wr + i * 16 + quad * 4 + r;
      int orig = g_idx[row];
      const float* xr = resf + (size_t)orig * 256;
      float ls_ = 0.f, ls2_ = 0.f;
#pragma unroll
      for (int j = 0; j < 8; j++) {
        int col = wc + j * 16 + l15;
        float h1 = acc[i][j][r] + bcol[j] + xr[col];
        acc[i][j][r] = h1;
        h1b[(size_t)row * 256 + col] = f2bs(h1);
        ls_ += h1;
        ls2_ += h1 * h1;
      }
      s1v[i][r] = ls_;
      s2v[i][r] = ls2_;
    }
  }
#pragma unroll
  for (int i = 0; i < 2; i++)
#pragma unroll
    for (int r = 0; r < 4; r++) {
#pragma unroll
      for (int o = 1; o < 16; o <<= 1) {
        s1v[i][r] += __shfl_xor(s1v[i][r], o);
        s2v[i][r] += __shfl_xor(s2v[i][r], o);
      }
    }
  if (l15 == 0) {
#pragma unroll
    for (int i = 0; i < 2; i++)
#pragma unroll
      for (int r = 0; r < 4; r++) {
        int lr = wr + i * 16 + quad * 4 + r;
        ps[lr][wave & 1] = s1v[i][r];
        ps2[lr][wave & 1] = s2v[i][r];
      }
  }
  __syncthreads();
#pragma unroll
  for (int i = 0; i < 2; i++) {
#pragma unroll
    for (int r = 0; r < 4; r++) {
      int lr = wr + i * 16 + quad * 4 + r;
      float S = ps[lr][0] + ps[lr][1];
      float S2 = ps2[lr][0] + ps2[lr][1];
      float m = S * (1.f / 256.f);
      float var = fmaxf(S2 * (1.f / 256.f) - m * m, 0.f);
      float rstd = rsqrtf(var + 1e-5f);
      int row = m0 + lr;
#pragma unroll
      for (int j = 0; j < 8; j++) {
        int col = wc + j * 16 + l15;
        float h2 = (acc[i][j][r] - m) * rstd * gcol[j] + bbcol[j];
        h2n[(size_t)row * 256 + col] = f2bs(h2);
      }
    }
  }
}

// ---------------- attention (compact, conflict-free V layout) ----------------
__global__ __launch_bounds__(256) void attn_k(
    const short* __restrict__ qkv, const float* __restrict__ amask,
    const int* __restrict__ g_idx, const int* __restrict__ startp,
    const int* __restrict__ cntp, short* __restrict__ ctx) {
  __shared__ __align__(16) short VF[2 * 12 * 64 * 8];
  __shared__ __align__(16) float ls[384];
  int bh = blockIdx.x >> 1, qhalf = blockIdx.x & 1;
  int bb = bh >> 3, h = bh & 7;
  int t = threadIdx.x;
  int start = startp[bb], cnt = cntp[bb];
  size_t base = (size_t)start * 768;
  for (int i = t; i < 1536; i += 256) {
    int k = i >> 2, cg = (i & 3) * 8;
    union { int4 v; short s[8]; } u;
    if (k < cnt) {
      u.v = *(const int4*)(qkv + base + (size_t)k * 768 + 512 + h * 32 + cg);
    } else {
      u.v = make_int4(0, 0, 0, 0);
    }
    int c = k >> 5, qd = (k >> 3) & 3, j = k & 7;
#pragma unroll
    for (int jj = 0; jj < 8; jj++) {
      int d = cg + jj;
      VF[((((d >> 4) * 12 + c) * 64) + qd * 16 + (d & 15)) * 8 + j] = u.s[jj];
    }
  }
  for (int i = t; i < 384; i += 256)
    ls[i] = (i < cnt) ? amask[g_idx[start + i]] : 0.f;
  __syncthreads();

  int wave = t >> 6, lane = t & 63;
  int ql = lane & 15, quad = lane >> 4;
  int addr0 = (((quad & 1) * 2) * 16 + ql) * 4;
  int addr1 = addr0 + 64;
  bool hiq = quad >= 2;
  int nt = (cnt + 15) >> 4;
  int nc = (cnt + 31) >> 5;

  for (int qt = qhalf + 2 * wave; qt < nt; qt += 8) {
    int q0 = qt * 16, qrow = q0 + ql;
    bf16x8 qf;
#pragma unroll
    for (int j = 0; j < 8; j++) qf[j] = 0;
    if (qrow < cnt)
      qf = *(const bf16x8*)(qkv + base + (size_t)qrow * 768 + h * 32 + quad * 8);

    f32x4 o0, o1;
#pragma unroll
    for (int r = 0; r < 4; r++) { o0[r] = 0.f; o1[r] = 0.f; }
    float lsum = 0.f;

    for (int c = 0; c < nc; c++) {
      int keyA = c * 32 + ql;
      int keyB = keyA + 16;
      bf16x8 kfA, kfB;
#pragma unroll
      for (int j = 0; j < 8; j++) { kfA[j] = 0; kfB[j] = 0; }
      if (keyA < cnt)
        kfA = *(const bf16x8*)(qkv + base + (size_t)keyA * 768 + 256 + h * 32 + quad * 8);
      if (keyB < cnt)
        kfB = *(const bf16x8*)(qkv + base + (size_t)keyB * 768 + 256 + h * 32 + quad * 8);
      f32x4 sa, sb;
#pragma unroll
      for (int r = 0; r < 4; r++) { sa[r] = 0.f; sb[r] = 0.f; }
      sa = __builtin_amdgcn_mfma_f32_16x16x32_bf16(kfA, qf, sa, 0, 0, 0);
      sb = __builtin_amdgcn_mfma_f32_16x16x32_bf16(kfB, qf, sb, 0, 0, 0);
      int kbase = c * 32 + quad * 4;
      float4 la = *(const float4*)&ls[kbase];
      float4 lb = *(const float4*)&ls[kbase + 16];
      float ea0 = (kbase + 0 < cnt) ? __expf(sa[0] * 0.17677669529663687f + la.x) : 0.f;
      float ea1 = (kbase + 1 < cnt) ? __expf(sa[1] * 0.17677669529663687f + la.y) : 0.f;
      float ea2 = (kbase + 2 < cnt) ? __expf(sa[2] * 0.17677669529663687f + la.z) : 0.f;
      float ea3 = (kbase + 3 < cnt) ? __expf(sa[3] * 0.17677669529663687f + la.w) : 0.f;
      float eb0 = (kbase + 16 < cnt) ? __expf(sb[0] * 0.17677669529663687f + lb.x) : 0.f;
      float eb1 = (kbase + 17 < cnt) ? __expf(sb[1] * 0.17677669529663687f + lb.y) : 0.f;
      float eb2 = (kbase + 18 < cnt) ? __expf(sb[2] * 0.17677669529663687f + lb.z) : 0.f;
      float eb3 = (kbase + 19 < cnt) ? __expf(sb[3] * 0.17677669529663687f + lb.w) : 0.f;
      lsum += (ea0 + ea1) + (ea2 + ea3) + (eb0 + eb1) + (eb2 + eb3);
      unsigned pA0 = packbf(ea0, ea1), pA1 = packbf(ea2, ea3);
      unsigned pB0 = packbf(eb0, eb1), pB1 = packbf(eb2, eb3);
      int s00 = __builtin_amdgcn_ds_bpermute(addr0, (int)pA0);
      int s10 = __builtin_amdgcn_ds_bpermute(addr0, (int)pB0);
      int s01 = __builtin_amdgcn_ds_bpermute(addr0, (int)pA1);
      int s11 = __builtin_amdgcn_ds_bpermute(addr0, (int)pB1);
      int s02 = __builtin_amdgcn_ds_bpermute(addr1, (int)pA0);
      int s12 = __builtin_amdgcn_ds_bpermute(addr1, (int)pB0);
      int s03 = __builtin_amdgcn_ds_bpermute(addr1, (int)pA1);
      int s13 = __builtin_amdgcn_ds_bpermute(addr1, (int)pB1);
      union { int i[4]; bf16x8 v; } pf;
      pf.i[0] = hiq ? s10 : s00;
      pf.i[1] = hiq ? s11 : s01;
      pf.i[2] = hiq ? s12 : s02;
      pf.i[3] = hiq ? s13 : s03;
      bf16x8 v0 = *(const bf16x8*)&VF[(c * 64 + lane) * 8];
      bf16x8 v1 = *(const bf16x8*)&VF[((12 + c) * 64 + lane) * 8];
      o0 = __builtin_amdgcn_mfma_f32_16x16x32_bf16(v0, pf.v, o0, 0, 0, 0);
      o1 = __builtin_amdgcn_mfma_f32_16x16x32_bf16(v1, pf.v, o1, 0, 0, 0);
    }
    lsum += __shfl_xor(lsum, 16);
    lsum += __shfl_xor(lsum, 32);
    float inv = 1.f / lsum;

    if (qrow < cnt) {
      size_t cb = ((size_t)(start + qrow)) * 256 + h * 32;
      uint2 w0, w1;
      w0.x = packbf(o0[0] * inv, o0[1] * inv);
      w0.y = packbf(o0[2] * inv, o0[3] * inv);
      w1.x = packbf(o1[0] * inv, o1[1] * inv);
      w1.y = packbf(o1[2] * inv, o1[3] * inv);
      *(uint2*)(ctx + cb + quad * 4) = w0;
      *(uint2*)(ctx + cb + 16 + quad * 4) = w1;
    }
  }
}

extern "C" void kernel_launch(void* const* d_in, const int* in_sizes, int n_in,
                              void* d_out, int out_size, void* d_ws,
                              size_t ws_size, hipStream_t stream) {
  const float* x = (const float*)d_in[0];
  const float* amask = (const float*)d_in[1];
  const float* wp_w = (const float*)d_in[2];
  const float* wp_b = (const float*)d_in[3];
  const float* a1_w = (const float*)d_in[4];
  const float* a1_b = (const float*)d_in[5];
  const float* a2_w = (const float*)d_in[6];
  const float* a2_b = (const float*)d_in[7];
  const float* ln1_g = (const float*)d_in[8];
  const float* ln1_b = (const float*)d_in[9];
  const float* wqkv = (const float*)d_in[10];
  const float* bqkv = (const float*)d_in[11];
  const float* wo = (const float*)d_in[12];
  const float* bo = (const float*)d_in[13];
  const float* ln2_g = (const float*)d_in[14];
  const float* ln2_b = (const float*)d_in[15];
  const float* w1 = (const float*)d_in[16];
  const float* b1 = (const float*)d_in[17];
  const float* w2 = (const float*)d_in[18];
  const float* b2 = (const float*)d_in[19];
  float* out = (float*)d_out;

  uint8_t* p = (uint8_t*)d_ws;
  float* weightsv = (float*)p; p += (size_t)TOKN * 4;
  int* selv = (int*)p;         p += (size_t)TOKN * 4;
  int* idxlv = (int*)p;        p += (size_t)TOKN * 4;
  int* gidxv = (int*)p;        p += (size_t)TOKN * 4;
  int* cntv = (int*)p;         p += 64 * 4;
  int* startv = (int*)p;       p += 64 * 4;
  int* mtotv = (int*)p;        p += 64 * 4;
  short* wqkvt = (short*)p;    p += (size_t)768 * 256 * 2;
  short* wot = (short*)p;      p += (size_t)256 * 256 * 2;
  short* w1t = (short*)p;      p += (size_t)1024 * 256 * 2;
  short* w2t = (short*)p;      p += (size_t)256 * 1024 * 2;
  short* h1bv = (short*)p;     p += (size_t)TOKN * 256 * 2;
  short* h2nv = (short*)p;     p += (size_t)TOKN * 256 * 2;
  short* ctxv = (short*)p;     p += (size_t)TOKN * 256 * 2;
  uint8_t* R = p;
  short* xnv = (short*)R;
  short* qkvv = (short*)(R + (size_t)TOKN * 256 * 2);
  short* actv = (short*)R;
  (void)idxlv;

  mega_k<<<dim3(7248), dim3(256), 0, stream>>>(
      x, ln1_g, ln1_b, wp_w, wp_b, xnv, weightsv, out,
      a1_w, a1_b, a2_w, a2_b, selv,
      wqkv, wo, w1, w2, wqkvt, wot, w1t, w2t);
  scan_k<<<dim3(64), dim3(512), 0, stream>>>(selv, gidxv, startv, cntv, mtotv,
                                             out + (size_t)TOKN * 256);
  gemm128_k<0, 128><<<dim3(6, 180), dim3(256), 0, stream>>>(
      xnv, wqkvt, bqkv, nullptr, nullptr, nullptr, gidxv, mtotv, qkvv, nullptr,
      768, 256);
  attn_k<<<dim3(1024), dim3(256), 0, stream>>>(qkvv, amask, gidxv, startv, cntv, ctxv);
  wo_ln_k<<<dim3(360), dim3(256), 0, stream>>>(ctxv, wot, bo, x, ln2_g, ln2_b,
                                               gidxv, mtotv, h1bv, h2nv);
  gemm128_k<2, 128><<<dim3(8, 180), dim3(256), 0, stream>>>(
      h2nv, w1t, b1, nullptr, nullptr, nullptr, gidxv, mtotv, actv, nullptr,
      1024, 256);
  gemm128_k<3, 64><<<dim3(4, 180), dim3(256), 0, stream>>>(
      actv, w2t, b2, nullptr, h1bv, weightsv, gidxv, mtotv, nullptr, out, 256, 1024);
}